// Round 7
// baseline (157.809 us; speedup 1.0000x reference)
//
#include <hip/hip_runtime.h>

#define BATCH 32
#define TT 8
#define VOCAB 2048
#define EMB 256
#define NG 8192          // 4*VOCAB
#define LAT 128
#define KTOT 2304        // EMB + VOCAB
#define NKT 72           // K-tiles of 32
#define NJT 128          // j-tiles of 16

#define WSCALE 4096.0f
#define ASCALE 16.0f
#define DQ (1.0f/65536.0f)   // exact 1/(WSCALE*ASCALE)

typedef float f32x4 __attribute__((ext_vector_type(4)));

// ws layout (float offsets)
#define EAC_OFF 0                      // 7*32 floats (pad to 256)
#define FLG_OFF 256                    // 128 flags, one per 64B line
#define ZP_OFF  4368                   // [7][32][128] partial Z sums
#define SP_OFF  33040                  // [7][32][128] partial S sums
#define AFX_OFF 61712                  // 7*2*8*64 ull x-embedding frags (all steps)
#define AFH_OFF 76048                  // 2 ping-pong bufs * 8192 ull h frags
#define BP_OFF  108816                 // 512*72*64 ull packed W (~18.9 MB)

#define AT_LD(p)    __hip_atomic_load((p),  __ATOMIC_RELAXED, __HIP_MEMORY_SCOPE_AGENT)
#define AT_ST(p,v)  __hip_atomic_store((p), (v), __ATOMIC_RELAXED, __HIP_MEMORY_SCOPE_AGENT)

__device__ __forceinline__ float sigmoidf_(float x){ return 1.f/(1.f+__expf(-x)); }
__device__ __forceinline__ float tanhf_(float x){
  x = fminf(fmaxf(x, -10.f), 10.f);
  float e = __expf(2.f*x);
  return (e-1.f)/(e+1.f);
}
// float -> OCP e4m3fn, RNE, saturate 448. Branchless, bit-identical to the
// frexpf-based version.
__device__ __forceinline__ unsigned char f2e4m3(float f){
  const unsigned int u = __float_as_uint(f);
  const unsigned int sign = (u >> 24) & 0x80u;
  const unsigned int au = u & 0x7FFFFFFFu;
  const unsigned int r = au + 0x0007FFFFu + ((au >> 20) & 1u);
  unsigned int code = (((r >> 23) - 120u) << 3) | ((r >> 20) & 7u);
  code = (code > 0x7Eu) ? 0x7Eu : code;
  const float a = __uint_as_float(au);
  const unsigned int sub = (unsigned int)rintf(a * 512.0f);
  code = (au < 0x3C800000u) ? sub : code;
  return (unsigned char)(sign | code);
}

// Pack W -> fp8 B-fragments via coalesced read + LDS transpose; fused init of
// persistent-kernel state (x-frags for ALL steps, h-frag buf1 zeros, out[:,0],
// per-block flags).
__global__ __launch_bounds__(256) void k_pack(
    const int* __restrict__ tok, const float* __restrict__ E,
    const float* __restrict__ Wi, const float* __restrict__ Wh,
    unsigned long long* __restrict__ Bp,
    unsigned long long* __restrict__ AfX, unsigned long long* __restrict__ AfH1,
    int* __restrict__ flg, float* __restrict__ out){
  const int tid = threadIdx.x;
  const int nb = blockIdx.x;            // 0..127
  const int kt = blockIdx.y;            // 0..71
  __shared__ unsigned char lds[32][64];
  {
    const int kl = tid >> 3;            // 0..31
    const int n0 = (tid & 7) * 8;
    const int k  = kt*32 + kl;
    const float* W = (k < EMB) ? (Wi + (size_t)k*NG) : (Wh + (size_t)(k-EMB)*NG);
    const float4 f0 = *(const float4*)(W + nb*64 + n0);
    const float4 f1 = *(const float4*)(W + nb*64 + n0 + 4);
    unsigned long long pk = 0ull;
    pk |= (unsigned long long)f2e4m3(f0.x*WSCALE);
    pk |= (unsigned long long)f2e4m3(f0.y*WSCALE) << 8;
    pk |= (unsigned long long)f2e4m3(f0.z*WSCALE) << 16;
    pk |= (unsigned long long)f2e4m3(f0.w*WSCALE) << 24;
    pk |= (unsigned long long)f2e4m3(f1.x*WSCALE) << 32;
    pk |= (unsigned long long)f2e4m3(f1.y*WSCALE) << 40;
    pk |= (unsigned long long)f2e4m3(f1.z*WSCALE) << 48;
    pk |= (unsigned long long)f2e4m3(f1.w*WSCALE) << 56;
    *(unsigned long long*)&lds[kl][n0] = pk;
  }
  __syncthreads();
  {
    const int ntl = tid >> 6, lane = tid & 63;
    const int kgrp = lane >> 4, n16 = lane & 15;
    unsigned long long pk = 0ull;
    #pragma unroll
    for (int p=0;p<8;p++)
      pk |= ((unsigned long long)lds[kgrp*8 + p][ntl*16 + n16]) << (8*p);
    Bp[((size_t)(nb*4 + ntl)*NKT + kt)*64 + lane] = pk;
  }
  // ---- fused init ----
  const int i = (kt*128 + nb)*256 + tid;
  if (i < 7*32*32){                     // x-embedding fragments, steps t=1..7
    const int s   = i >> 10;            // slot = t-1
    const int rem = i & 1023;
    const int b   = rem >> 5;
    const int kgi = rem & 31;           // which 8-byte k-group of EMB
    const int tk  = tok[b*TT + s];
    const float4 e0 = *(const float4*)(E + (size_t)tk*EMB + kgi*8);
    const float4 e1 = *(const float4*)(E + (size_t)tk*EMB + kgi*8 + 4);
    unsigned long long pk = 0ull;
    pk |= (unsigned long long)f2e4m3(e0.x*ASCALE);
    pk |= (unsigned long long)f2e4m3(e0.y*ASCALE) << 8;
    pk |= (unsigned long long)f2e4m3(e0.z*ASCALE) << 16;
    pk |= (unsigned long long)f2e4m3(e0.w*ASCALE) << 24;
    pk |= (unsigned long long)f2e4m3(e1.x*ASCALE) << 32;
    pk |= (unsigned long long)f2e4m3(e1.y*ASCALE) << 40;
    pk |= (unsigned long long)f2e4m3(e1.z*ASCALE) << 48;
    pk |= (unsigned long long)f2e4m3(e1.w*ASCALE) << 56;
    AfX[((size_t)((s*2 + (b>>4))*8 + (kgi>>2)))*64 + (kgi&3)*16 + (b&15)] = pk;
  }
  if (i < 8192) AfH1[i] = 0ull;         // t=1 reads parity-1 h-buffer: h0 = 0
  if (i < BATCH*LAT)
    out[(size_t)((i>>7)*TT + 0)*LAT + (i&(LAT-1))] = 0.f;  // t=0: z=0 exactly
  if (i < 4096) flg[i] = 0;
}

// All 7 LSTM steps + outputs in ONE persistent kernel, flat flag-synchronized.
// 128 blocks (one per jt), 256 threads = 4 waves = 4 gates; each wave does
// M=32 (BOTH batch halves) x N=16, sharing one B fragment per kt between two
// accumulators. B is STREAMED from Bp each step (no fake register residency):
// each Bp line is read by exactly one block -> per-XCD working set 2.4 MB,
// L2-resident after step 1. h-frags staged via LDS (both planes, 64 KB).
// Per-output MFMA order (kt ascending, x then h) and cell math identical to
// the verified version -> bit-identical output.
__global__ __launch_bounds__(256, 1) void k_fused(
    const int* __restrict__ tok, const float* __restrict__ bias,
    float* __restrict__ out, float* __restrict__ Zp, float* __restrict__ Sp,
    float* __restrict__ Eac, const unsigned long long* __restrict__ AfX,
    unsigned long long* __restrict__ AfH, const unsigned long long* __restrict__ Bp,
    int* __restrict__ flg){
  const int tid = threadIdx.x;
  const int bid = blockIdx.x;           // = jt
  const int jt = bid;
  const int g = tid >> 6, lane = tid & 63;
  const int quad = lane >> 4, col = lane & 15;

  __shared__ float gsh[2][4][16][16];   // [mh][gate][row][col]
  __shared__ long hlds[2][64][64];      // 64 KB: h-frag stage, both mh planes
  __shared__ unsigned char hsh[512];
  __shared__ float zsh[2];

  const long* __restrict__ BpV = (const long*)Bp;
  const size_t bbase = (size_t)(g*NJT + jt)*NKT*64 + lane;

  // epilogue thread mapping: thread owns (b16, jj) -> outputs b16 and b16+16
  const int b16 = tid >> 4, jj = tid & 15;
  const int j = jt*16 + jj;
  const float bi  = bias[j];
  const float bff = bias[j + VOCAB];
  const float bgg = bias[j + 2*VOCAB];
  const float boo = bias[j + 3*VOCAB];
  const int hoff = ((jj>>3)&1)*128 + b16*8 + (jj&7);   // byte in hsh (per mh +256)
  float hreg0 = 0.f, creg0 = 0.f, hreg1 = 0.f, creg1 = 0.f;

  for (int t=1; t<TT; t++){
    // A: x-part MFMA for both mh planes — independent of other blocks
    const long* __restrict__ aX = (const long*)AfX + (size_t)((t-1)*2)*512 + lane;
    f32x4 acc0 = {0,0,0,0}, acc1 = {0,0,0,0};
    #pragma unroll
    for (int kt=0; kt<8; kt++){
      const long bv = BpV[bbase + (size_t)kt*64];
      acc0 = __builtin_amdgcn_mfma_f32_16x16x32_fp8_fp8(aX[(size_t)kt*64], bv, acc0, 0,0,0);
      acc1 = __builtin_amdgcn_mfma_f32_16x16x32_fp8_fp8(aX[(size_t)(512 + kt*64)], bv, acc1, 0,0,0);
    }

    // B: flat wait for all 128 producers of step t-1 (64 pollers x 2 flags)
    if (t >= 2){
      const int want = t-1;
      if (tid < 64){
        for (;;){
          int done = 1;
          #pragma unroll
          for (int q2=0;q2<2;q2++)
            done &= (AT_LD(&flg[(tid*2+q2)*16]) >= want) ? 1 : 0;
          if (done) break;
          __builtin_amdgcn_s_sleep(1);
        }
      }
      asm volatile("" ::: "memory");
    }
    __syncthreads();

    // C: stage h-frags to LDS — wave g loads rows g*16..g*16+15 of BOTH planes
    {
      unsigned long long* aH = AfH + (size_t)(t&1)*8192;
      long hl0[16], hl1[16];
      #pragma unroll
      for (int i=0;i<16;i++){
        hl0[i] = (long)AT_LD(&aH[(size_t)(g*16+i)*64 + lane]);
        hl1[i] = (long)AT_LD(&aH[(size_t)(4096 + (g*16+i)*64) + lane]);
      }
      #pragma unroll
      for (int i=0;i<16;i++){
        hlds[0][g*16+i][lane] = hl0[i];
        hlds[1][g*16+i][lane] = hl1[i];
      }
    }
    __syncthreads();

    // D: h-part MFMA from LDS, B streamed from L2 — identical kt order
    #pragma unroll
    for (int kt=8; kt<NKT; kt++){
      const long bv = BpV[bbase + (size_t)kt*64];
      acc0 = __builtin_amdgcn_mfma_f32_16x16x32_fp8_fp8(hlds[0][kt-8][lane], bv, acc0, 0,0,0);
      acc1 = __builtin_amdgcn_mfma_f32_16x16x32_fp8_fp8(hlds[1][kt-8][lane], bv, acc1, 0,0,0);
    }
    #pragma unroll
    for (int r=0;r<4;r++){
      gsh[0][g][quad*4 + r][col] = acc0[r];
      gsh[1][g][quad*4 + r][col] = acc1[r];
    }
    __syncthreads();

    // E: fused cell, two outputs per thread (b16, b16+16); same math/order
    {
      const int b0 = b16;
      const float ip = gsh[0][0][b16][jj]*DQ + bi;
      const float fp = gsh[0][1][b16][jj]*DQ + bff;
      const float gg = gsh[0][2][b16][jj]*DQ + bgg;
      const float op = gsh[0][3][b16][jj]*DQ + boo;
      const float cn = sigmoidf_(fp)*creg0 + sigmoidf_(ip)*tanhf_(gg);
      const float hn = sigmoidf_(op)*tanhf_(cn);
      if (tok[b0*TT + (t-1)] != 0){ hreg0 = hn; creg0 = cn; }
      hsh[hoff] = f2e4m3(ASCALE*hreg0);
      const int sj = tok[b0*TT + t];
      const float e = __expf(hreg0);
      if (j == sj) AT_ST(&Eac[(t-1)*32 + b0], e);
      float z = e, s = (j < sj) ? e : 0.f;
      #pragma unroll
      for (int m=1; m<16; m<<=1){ z += __shfl_xor(z, m); s += __shfl_xor(s, m); }
      if (jj == 0){
        AT_ST(&Zp[((size_t)(t-1)*32 + b0)*128 + jt], z);
        AT_ST(&Sp[((size_t)(t-1)*32 + b0)*128 + jt], s);
      }
    }
    {
      const int b1 = 16 + b16;
      const float ip = gsh[1][0][b16][jj]*DQ + bi;
      const float fp = gsh[1][1][b16][jj]*DQ + bff;
      const float gg = gsh[1][2][b16][jj]*DQ + bgg;
      const float op = gsh[1][3][b16][jj]*DQ + boo;
      const float cn = sigmoidf_(fp)*creg1 + sigmoidf_(ip)*tanhf_(gg);
      const float hn = sigmoidf_(op)*tanhf_(cn);
      if (tok[b1*TT + (t-1)] != 0){ hreg1 = hn; creg1 = cn; }
      hsh[256 + hoff] = f2e4m3(ASCALE*hreg1);
      const int sj = tok[b1*TT + t];
      const float e = __expf(hreg1);
      if (j == sj) AT_ST(&Eac[(t-1)*32 + b1], e);
      float z = e, s = (j < sj) ? e : 0.f;
      #pragma unroll
      for (int m=1; m<16; m<<=1){ z += __shfl_xor(z, m); s += __shfl_xor(s, m); }
      if (jj == 0){
        AT_ST(&Zp[((size_t)(t-1)*32 + b1)*128 + jt], z);
        AT_ST(&Sp[((size_t)(t-1)*32 + b1)*128 + jt], s);
      }
    }
    __syncthreads();                    // hsh complete

    // F: publish h-frags (both mh chunks), drain, post flag
    if (tid < 64){
      const int pm = tid >> 5, w = tid & 31;
      unsigned long long* dst =
        (unsigned long long*)((unsigned char*)AfH + (size_t)((t&1)^1)*65536
                              + (size_t)(pm*64 + (jt>>1))*512 + (size_t)(jt&1)*256);
      AT_ST(&dst[w], ((const unsigned long long*)hsh)[pm*32 + w]);
    }
    asm volatile("s_waitcnt vmcnt(0)" ::: "memory");  // all sc1 stores at L3
    __syncthreads();
    if (tid == 0) AT_ST(&flg[bid*16], t);

    // G: out[:, t-1] from slot t-2 — after the flag post, off the critical path
    if (t >= 2 && bid < BATCH){
      const int s = t-2;
      if (tid < 64){
        float zl = AT_LD(&Zp[((size_t)s*32+bid)*128 + tid])
                 + AT_LD(&Zp[((size_t)s*32+bid)*128 + tid + 64]);
        float sl = AT_LD(&Sp[((size_t)s*32+bid)*128 + tid])
                 + AT_LD(&Sp[((size_t)s*32+bid)*128 + tid + 64]);
        #pragma unroll
        for (int m=1; m<64; m<<=1){ zl += __shfl_xor(zl, m); sl += __shfl_xor(sl, m); }
        if (tid == 0){ zsh[0] = zl; zsh[1] = sl; }
      }
      __syncthreads();
      if (tid < LAT){
        const float Ej = AT_LD(&Eac[s*32 + bid]);
        out[((size_t)bid*TT + (t-1))*LAT + tid] = (3.f*zsh[1] + 1.5f*Ej)/zsh[0];
      }
    }
  }

  // final: wait for all step-7 flags, then out[:,7] from slot 6
  if (bid < BATCH){
    if (tid < 64){
      for (;;){
        int done = 1;
        #pragma unroll
        for (int q2=0;q2<2;q2++)
          done &= (AT_LD(&flg[(tid*2+q2)*16]) >= TT-1) ? 1 : 0;
        if (done) break;
        __builtin_amdgcn_s_sleep(1);
      }
    }
    asm volatile("" ::: "memory");
    __syncthreads();
    const int s = TT-2;                 // slot 6
    if (tid < 64){
      float zl = AT_LD(&Zp[((size_t)s*32+bid)*128 + tid])
               + AT_LD(&Zp[((size_t)s*32+bid)*128 + tid + 64]);
      float sl = AT_LD(&Sp[((size_t)s*32+bid)*128 + tid])
               + AT_LD(&Sp[((size_t)s*32+bid)*128 + tid + 64]);
      #pragma unroll
      for (int m=1; m<64; m<<=1){ zl += __shfl_xor(zl, m); sl += __shfl_xor(sl, m); }
      if (tid == 0){ zsh[0] = zl; zsh[1] = sl; }
    }
    __syncthreads();
    if (tid < LAT){
      const float Ej = AT_LD(&Eac[s*32 + bid]);
      out[((size_t)bid*TT + (TT-1))*LAT + tid] = (3.f*zsh[1] + 1.5f*Ej)/zsh[0];
    }
  }
}

extern "C" void kernel_launch(void* const* d_in, const int* in_sizes, int n_in,
                              void* d_out, int out_size, void* d_ws, size_t ws_size,
                              hipStream_t stream){
  const int*   tok  = (const int*)d_in[0];
  const float* E    = (const float*)d_in[1];
  const float* Wi   = (const float*)d_in[2];
  const float* Wh   = (const float*)d_in[3];
  const float* bias = (const float*)d_in[4];
  float* out = (float*)d_out;
  float* ws  = (float*)d_ws;
  float* Eac = ws + EAC_OFF;
  int*   flg = (int*)(ws + FLG_OFF);
  float* Zp  = ws + ZP_OFF;
  float* Sp  = ws + SP_OFF;
  unsigned long long* AfX = (unsigned long long*)(ws + AFX_OFF);
  unsigned long long* AfH = (unsigned long long*)(ws + AFH_OFF);
  unsigned long long* Bp  = (unsigned long long*)(ws + BP_OFF);

  k_pack<<<dim3(128, NKT), 256, 0, stream>>>(tok, E, Wi, Wh, Bp, AfX, AfH + 8192,
                                             flg, out);
  k_fused<<<128, 256, 0, stream>>>(tok, bias, out, Zp, Sp, Eac, AfX, AfH, Bp, flg);
}

// Round 8
// 141.596 us; speedup vs baseline: 1.1145x; 1.1145x over previous
//
#include <hip/hip_runtime.h>

#define BATCH 32
#define TT 8
#define VOCAB 2048
#define EMB 256
#define NG 8192          // 4*VOCAB
#define LAT 128
#define KTOT 2304        // EMB + VOCAB
#define NKT 72           // K-tiles of 32
#define NNT 512          // N-tiles of 16
#define NJT 128          // j-tiles of 16

#define WSCALE 4096.0f
#define ASCALE 16.0f
#define DQ (1.0f/65536.0f)   // exact 1/(WSCALE*ASCALE)

typedef float f32x4 __attribute__((ext_vector_type(4)));

// ws layout (float offsets)
#define EAC_OFF 0                      // 7*32 floats (pad to 256)
#define FLG_OFF 256                    // 256 flags, one per 64B line (4096 ints)
#define ZP_OFF  4352                   // [7][32][128] partial Z sums
#define SP_OFF  33024                  // [7][32][128] partial S sums
#define AFX_OFF 61696                  // 7*2*8*64 ull x-embedding frags (all steps)
#define AFH_OFF 76032                  // 2 ping-pong bufs * 8192 ull h frags
#define BP_OFF  108800                 // 512*72*64 ull packed W (~18.9 MB)

#define AT_LD(p)    __hip_atomic_load((p),  __ATOMIC_RELAXED, __HIP_MEMORY_SCOPE_AGENT)
#define AT_ST(p,v)  __hip_atomic_store((p), (v), __ATOMIC_RELAXED, __HIP_MEMORY_SCOPE_AGENT)

__device__ __forceinline__ float sigmoidf_(float x){ return 1.f/(1.f+__expf(-x)); }
__device__ __forceinline__ float tanhf_(float x){
  x = fminf(fmaxf(x, -10.f), 10.f);
  float e = __expf(2.f*x);
  return (e-1.f)/(e+1.f);
}
// float -> OCP e4m3fn, RNE, saturate 448. Branchless, bit-identical to the
// frexpf-based version (integer-domain RNE == frexp/rint RNE; the a>=464
// early-out == post-round saturation; subnormal path unchanged).
__device__ __forceinline__ unsigned char f2e4m3(float f){
  const unsigned int u = __float_as_uint(f);
  const unsigned int sign = (u >> 24) & 0x80u;
  const unsigned int au = u & 0x7FFFFFFFu;
  const unsigned int r = au + 0x0007FFFFu + ((au >> 20) & 1u);
  unsigned int code = (((r >> 23) - 120u) << 3) | ((r >> 20) & 7u);
  code = (code > 0x7Eu) ? 0x7Eu : code;
  const float a = __uint_as_float(au);
  const unsigned int sub = (unsigned int)rintf(a * 512.0f);
  code = (au < 0x3C800000u) ? sub : code;
  return (unsigned char)(sign | code);
}

// Pack W -> fp8 B-fragments via coalesced read + LDS transpose; fused init of
// persistent-kernel state (x-frags for ALL steps, h-frag buf1 zeros, out[:,0],
// per-block flags).
__global__ __launch_bounds__(256) void k_pack(
    const int* __restrict__ tok, const float* __restrict__ E,
    const float* __restrict__ Wi, const float* __restrict__ Wh,
    unsigned long long* __restrict__ Bp,
    unsigned long long* __restrict__ AfX, unsigned long long* __restrict__ AfH1,
    int* __restrict__ flg, float* __restrict__ out){
  const int tid = threadIdx.x;
  const int nb = blockIdx.x;            // 0..127
  const int kt = blockIdx.y;            // 0..71
  __shared__ unsigned char lds[32][64];
  {
    const int kl = tid >> 3;            // 0..31
    const int n0 = (tid & 7) * 8;
    const int k  = kt*32 + kl;
    const float* W = (k < EMB) ? (Wi + (size_t)k*NG) : (Wh + (size_t)(k-EMB)*NG);
    const float4 f0 = *(const float4*)(W + nb*64 + n0);
    const float4 f1 = *(const float4*)(W + nb*64 + n0 + 4);
    unsigned long long pk = 0ull;
    pk |= (unsigned long long)f2e4m3(f0.x*WSCALE);
    pk |= (unsigned long long)f2e4m3(f0.y*WSCALE) << 8;
    pk |= (unsigned long long)f2e4m3(f0.z*WSCALE) << 16;
    pk |= (unsigned long long)f2e4m3(f0.w*WSCALE) << 24;
    pk |= (unsigned long long)f2e4m3(f1.x*WSCALE) << 32;
    pk |= (unsigned long long)f2e4m3(f1.y*WSCALE) << 40;
    pk |= (unsigned long long)f2e4m3(f1.z*WSCALE) << 48;
    pk |= (unsigned long long)f2e4m3(f1.w*WSCALE) << 56;
    *(unsigned long long*)&lds[kl][n0] = pk;
  }
  __syncthreads();
  {
    const int ntl = tid >> 6, lane = tid & 63;
    const int kgrp = lane >> 4, n16 = lane & 15;
    unsigned long long pk = 0ull;
    #pragma unroll
    for (int p=0;p<8;p++)
      pk |= ((unsigned long long)lds[kgrp*8 + p][ntl*16 + n16]) << (8*p);
    Bp[((size_t)(nb*4 + ntl)*NKT + kt)*64 + lane] = pk;
  }
  // ---- fused init ----
  const int i = (kt*128 + nb)*256 + tid;
  if (i < 7*32*32){                     // x-embedding fragments, steps t=1..7
    const int s   = i >> 10;            // slot = t-1
    const int rem = i & 1023;
    const int b   = rem >> 5;
    const int kgi = rem & 31;           // which 8-byte k-group of EMB
    const int tk  = tok[b*TT + s];
    const float4 e0 = *(const float4*)(E + (size_t)tk*EMB + kgi*8);
    const float4 e1 = *(const float4*)(E + (size_t)tk*EMB + kgi*8 + 4);
    unsigned long long pk = 0ull;
    pk |= (unsigned long long)f2e4m3(e0.x*ASCALE);
    pk |= (unsigned long long)f2e4m3(e0.y*ASCALE) << 8;
    pk |= (unsigned long long)f2e4m3(e0.z*ASCALE) << 16;
    pk |= (unsigned long long)f2e4m3(e0.w*ASCALE) << 24;
    pk |= (unsigned long long)f2e4m3(e1.x*ASCALE) << 32;
    pk |= (unsigned long long)f2e4m3(e1.y*ASCALE) << 40;
    pk |= (unsigned long long)f2e4m3(e1.z*ASCALE) << 48;
    pk |= (unsigned long long)f2e4m3(e1.w*ASCALE) << 56;
    AfX[((size_t)((s*2 + (b>>4))*8 + (kgi>>2)))*64 + (kgi&3)*16 + (b&15)] = pk;
  }
  if (i < 8192) AfH1[i] = 0ull;         // t=1 reads parity-1 h-buffer: h0 = 0
  if (i < BATCH*LAT)
    out[(size_t)((i>>7)*TT + 0)*LAT + (i&(LAT-1))] = 0.f;  // t=0: z=0 exactly
  if (i < 4096) flg[i] = 0;
}

// All 7 LSTM steps + outputs in ONE persistent kernel, flat flag-synchronized.
// 256 blocks = (jt 0..127) x (mh 0..1); 4 waves = 4 gates; wave M=16 x N=16.
// B fragments pinned in VGPRs for the whole sequence. Cross-block data moves
// via relaxed agent-scope (sc1) atomics; per-block flag lines; ordering =
// vmcnt(0) + __syncthreads before the flag store. Per step: x-MFMAs hoisted
// before the flag wait; h-frags staged once per block through LDS (4x less L3
// traffic than per-wave loads); out-column write moved off the critical path.
__global__ __launch_bounds__(256, 1) void k_fused(
    const int* __restrict__ tok, const float* __restrict__ bias,
    float* __restrict__ out, float* __restrict__ Zp, float* __restrict__ Sp,
    float* __restrict__ Eac, const unsigned long long* __restrict__ AfX,
    unsigned long long* __restrict__ AfH, const unsigned long long* __restrict__ Bp,
    int* __restrict__ flg){
  const int tid = threadIdx.x;
  const int bid = blockIdx.x;
  const int jt = bid & 127, mh = bid >> 7;
  const int g = tid >> 6, lane = tid & 63;
  const int quad = lane >> 4, col = lane & 15;

  __shared__ float gsh[4][16][16];
  __shared__ long hlds[64][64];         // 32 KB: h-frag stage, conflict-free b64
  __shared__ unsigned char hsh[256];
  __shared__ float zsh[2];

  // ---- persistent B fragments: one n-tile per wave, full K, in registers ----
  const long* __restrict__ BpV = (const long*)Bp;
  const size_t bbase = (size_t)(g*NJT + jt)*NKT*64 + lane;
  long Breg[NKT];
  #pragma unroll
  for (int i=0;i<NKT;i++) Breg[i] = BpV[bbase + (size_t)i*64];
  #pragma unroll
  for (int i=0;i<NKT;i++) asm volatile("" : "+v"(Breg[i]));  // pin: no sinking

  // epilogue thread mapping: thread owns (b, j)
  const int b16 = tid >> 4, jj = tid & 15;
  const int b = mh*16 + b16;
  const int j = jt*16 + jj;
  const float bi  = bias[j];
  const float bff = bias[j + VOCAB];
  const float bgg = bias[j + 2*VOCAB];
  const float boo = bias[j + 3*VOCAB];
  const int hoff = ((jj>>3)&1)*128 + b16*8 + (jj&7);           // byte in hsh
  const size_t bofs = (size_t)(mh*64 + (jt>>1))*512 + (size_t)(jt&1)*256;
  float hreg = 0.f, creg = 0.f;

  for (int t=1; t<TT; t++){
    // A: x-part MFMA — independent of other blocks' step t-1
    const long* __restrict__ aX = (const long*)AfX + (size_t)((t-1)*2 + mh)*512 + lane;
    f32x4 acc = {0,0,0,0};
    #pragma unroll
    for (int kt=0; kt<8; kt++)
      acc = __builtin_amdgcn_mfma_f32_16x16x32_fp8_fp8(aX[(size_t)kt*64], Breg[kt], acc, 0,0,0);

    // B: wait for all 256 producers of step t-1 (64 pollers x 4 flags each —
    // bounds the L3 poll storm that competes with the h-frag loads)
    if (t >= 2){
      const int want = t-1;
      if (tid < 64){
        for (;;){
          int done = 1;
          #pragma unroll
          for (int q2=0;q2<4;q2++)
            done &= (AT_LD(&flg[(tid*4+q2)*16]) >= want) ? 1 : 0;
          if (done) break;
          __builtin_amdgcn_s_sleep(2);
        }
      }
      asm volatile("" ::: "memory");
    }
    __syncthreads();

    // C: stage h-frags to LDS — each wave loads only its 16 rows (sc1)
    {
      unsigned long long* aH = AfH + (size_t)(t&1)*8192 + (size_t)mh*4096;
      long hl[16];
      #pragma unroll
      for (int i=0;i<16;i++)
        hl[i] = (long)AT_LD(&aH[(size_t)(g*16+i)*64 + lane]);
      #pragma unroll
      for (int i=0;i<16;i++) hlds[g*16+i][lane] = hl[i];
    }
    __syncthreads();

    // D: h-part MFMA from LDS — identical kt order -> bit-identical acc
    #pragma unroll
    for (int kt=8; kt<NKT; kt++)
      acc = __builtin_amdgcn_mfma_f32_16x16x32_fp8_fp8(hlds[kt-8][lane], Breg[kt], acc, 0,0,0);
    #pragma unroll
    for (int r=0;r<4;r++) gsh[g][quad*4 + r][col] = acc[r];
    __syncthreads();

    // E: fused cell (same math/order as verified version)
    const float ip = gsh[0][b16][jj]*DQ + bi;
    const float fp = gsh[1][b16][jj]*DQ + bff;
    const float gg = gsh[2][b16][jj]*DQ + bgg;
    const float op = gsh[3][b16][jj]*DQ + boo;
    const float cn = sigmoidf_(fp)*creg + sigmoidf_(ip)*tanhf_(gg);
    const float hn = sigmoidf_(op)*tanhf_(cn);
    if (tok[b*TT + (t-1)] != 0){ hreg = hn; creg = cn; }
    hsh[hoff] = f2e4m3(ASCALE*hreg);
    const int sj = tok[b*TT + t];
    const float e = __expf(hreg);       // h in (-1,1): no max-pass
    if (j == sj) AT_ST(&Eac[(t-1)*32 + b], e);   // unique writer
    float z = e, s = (j < sj) ? e : 0.f;
    #pragma unroll
    for (int m=1; m<16; m<<=1){ z += __shfl_xor(z, m); s += __shfl_xor(s, m); }
    if (jj == 0){                       // contention-free partials (per jt)
      AT_ST(&Zp[((size_t)(t-1)*32 + b)*128 + jt], z);
      AT_ST(&Sp[((size_t)(t-1)*32 + b)*128 + jt], s);
    }
    __syncthreads();                    // hsh complete

    // F: publish h-frags, drain, post flag
    if (tid < 32){
      unsigned long long* dst =
        (unsigned long long*)((unsigned char*)AfH + (size_t)((t&1)^1)*65536 + bofs);
      AT_ST(&dst[tid], ((const unsigned long long*)hsh)[tid]);
    }
    asm volatile("s_waitcnt vmcnt(0)" ::: "memory");  // all sc1 stores at L3
    __syncthreads();
    if (tid == 0) AT_ST(&flg[bid*16], t);

    // G: out[:, t-1] from slot t-2 — after the flag post, off the critical path
    if (t >= 2 && bid < BATCH){
      const int s = t-2;
      if (tid < 64){
        float zl = AT_LD(&Zp[((size_t)s*32+bid)*128 + tid])
                 + AT_LD(&Zp[((size_t)s*32+bid)*128 + tid + 64]);
        float sl = AT_LD(&Sp[((size_t)s*32+bid)*128 + tid])
                 + AT_LD(&Sp[((size_t)s*32+bid)*128 + tid + 64]);
        #pragma unroll
        for (int m=1; m<64; m<<=1){ zl += __shfl_xor(zl, m); sl += __shfl_xor(sl, m); }
        if (tid == 0){ zsh[0] = zl; zsh[1] = sl; }
      }
      __syncthreads();
      if (tid < LAT){
        const float Ej = AT_LD(&Eac[s*32 + bid]);
        out[((size_t)bid*TT + (t-1))*LAT + tid] = (3.f*zsh[1] + 1.5f*Ej)/zsh[0];
      }
    }
  }

  // final: wait for all step-7 flags, then out[:,7] from slot 6
  if (bid < BATCH){
    while (AT_LD(&flg[tid*16]) < TT-1) __builtin_amdgcn_s_sleep(1);
    asm volatile("" ::: "memory");
    __syncthreads();
    const int s = TT-2;                 // slot 6
    if (tid < 64){
      float zl = AT_LD(&Zp[((size_t)s*32+bid)*128 + tid])
               + AT_LD(&Zp[((size_t)s*32+bid)*128 + tid + 64]);
      float sl = AT_LD(&Sp[((size_t)s*32+bid)*128 + tid])
               + AT_LD(&Sp[((size_t)s*32+bid)*128 + tid + 64]);
      #pragma unroll
      for (int m=1; m<64; m<<=1){ zl += __shfl_xor(zl, m); sl += __shfl_xor(sl, m); }
      if (tid == 0){ zsh[0] = zl; zsh[1] = sl; }
    }
    __syncthreads();
    if (tid < LAT){
      const float Ej = AT_LD(&Eac[s*32 + bid]);
      out[((size_t)bid*TT + (TT-1))*LAT + tid] = (3.f*zsh[1] + 1.5f*Ej)/zsh[0];
    }
  }
}

extern "C" void kernel_launch(void* const* d_in, const int* in_sizes, int n_in,
                              void* d_out, int out_size, void* d_ws, size_t ws_size,
                              hipStream_t stream){
  const int*   tok  = (const int*)d_in[0];
  const float* E    = (const float*)d_in[1];
  const float* Wi   = (const float*)d_in[2];
  const float* Wh   = (const float*)d_in[3];
  const float* bias = (const float*)d_in[4];
  float* out = (float*)d_out;
  float* ws  = (float*)d_ws;
  float* Eac = ws + EAC_OFF;
  int*   flg = (int*)(ws + FLG_OFF);
  float* Zp  = ws + ZP_OFF;
  float* Sp  = ws + SP_OFF;
  unsigned long long* AfX = (unsigned long long*)(ws + AFX_OFF);
  unsigned long long* AfH = (unsigned long long*)(ws + AFH_OFF);
  unsigned long long* Bp  = (unsigned long long*)(ws + BP_OFF);

  k_pack<<<dim3(128, NKT), 256, 0, stream>>>(tok, E, Wi, Wh, Bp, AfX, AfH + 8192,
                                             flg, out);
  k_fused<<<256, 256, 0, stream>>>(tok, bias, out, Zp, Sp, Eac, AfX, AfH, Bp, flg);
}

// Round 10
// 139.568 us; speedup vs baseline: 1.1307x; 1.0145x over previous
//
#include <hip/hip_runtime.h>

#define BATCH 32
#define TT 8
#define VOCAB 2048
#define EMB 256
#define NG 8192          // 4*VOCAB
#define LAT 128
#define KTOT 2304        // EMB + VOCAB
#define NKT 72           // K-tiles of 32
#define NNT 512          // N-tiles of 16
#define NJT 128          // j-tiles of 16

#define WSCALE 4096.0f
#define ASCALE 16.0f
#define DQ (1.0f/65536.0f)   // exact 1/(WSCALE*ASCALE)

typedef float f32x4 __attribute__((ext_vector_type(4)));

// ws layout (float offsets)
#define EAC_OFF 0                      // 7*32 floats (pad to 256)
#define FLG_OFF 256                    // 256 flags, one per 64B line (4096 ints)
#define ZP_OFF  4352                   // [7][32][128] partial Z sums
#define SP_OFF  33024                  // [7][32][128] partial S sums
#define AFX_OFF 61696                  // 7*2*8*64 ull x-embedding frags (all steps)
#define AFH_OFF 76032                  // 2 ping-pong bufs * 8192 ull h frags
#define BP_OFF  108800                 // 512*72*64 ull packed W (~18.9 MB)

#define AT_LD(p)    __hip_atomic_load((p),  __ATOMIC_RELAXED, __HIP_MEMORY_SCOPE_AGENT)
#define AT_ST(p,v)  __hip_atomic_store((p), (v), __ATOMIC_RELAXED, __HIP_MEMORY_SCOPE_AGENT)

__device__ __forceinline__ float sigmoidf_(float x){ return 1.f/(1.f+__expf(-x)); }
__device__ __forceinline__ float tanhf_(float x){
  x = fminf(fmaxf(x, -10.f), 10.f);
  float e = __expf(2.f*x);
  return (e-1.f)/(e+1.f);
}
// float -> OCP e4m3fn, RNE, saturate 448. Branchless, bit-identical to the
// frexpf-based version (integer-domain RNE == frexp/rint RNE; the a>=464
// early-out == post-round saturation; subnormal path unchanged).
__device__ __forceinline__ unsigned char f2e4m3(float f){
  const unsigned int u = __float_as_uint(f);
  const unsigned int sign = (u >> 24) & 0x80u;
  const unsigned int au = u & 0x7FFFFFFFu;
  const unsigned int r = au + 0x0007FFFFu + ((au >> 20) & 1u);
  unsigned int code = (((r >> 23) - 120u) << 3) | ((r >> 20) & 7u);
  code = (code > 0x7Eu) ? 0x7Eu : code;
  const float a = __uint_as_float(au);
  const unsigned int sub = (unsigned int)rintf(a * 512.0f);
  code = (au < 0x3C800000u) ? sub : code;
  return (unsigned char)(sign | code);
}

// Pack W -> fp8 B-fragments via coalesced read + LDS transpose; fused init of
// persistent-kernel state (x-frags for ALL steps, h-frag buf1 zeros, out[:,0],
// per-block flags).
__global__ __launch_bounds__(256) void k_pack(
    const int* __restrict__ tok, const float* __restrict__ E,
    const float* __restrict__ Wi, const float* __restrict__ Wh,
    unsigned long long* __restrict__ Bp,
    unsigned long long* __restrict__ AfX, unsigned long long* __restrict__ AfH1,
    int* __restrict__ flg, float* __restrict__ out){
  const int tid = threadIdx.x;
  const int nb = blockIdx.x;            // 0..127
  const int kt = blockIdx.y;            // 0..71
  __shared__ unsigned char lds[32][64];
  {
    const int kl = tid >> 3;            // 0..31
    const int n0 = (tid & 7) * 8;
    const int k  = kt*32 + kl;
    const float* W = (k < EMB) ? (Wi + (size_t)k*NG) : (Wh + (size_t)(k-EMB)*NG);
    const float4 f0 = *(const float4*)(W + nb*64 + n0);
    const float4 f1 = *(const float4*)(W + nb*64 + n0 + 4);
    unsigned long long pk = 0ull;
    pk |= (unsigned long long)f2e4m3(f0.x*WSCALE);
    pk |= (unsigned long long)f2e4m3(f0.y*WSCALE) << 8;
    pk |= (unsigned long long)f2e4m3(f0.z*WSCALE) << 16;
    pk |= (unsigned long long)f2e4m3(f0.w*WSCALE) << 24;
    pk |= (unsigned long long)f2e4m3(f1.x*WSCALE) << 32;
    pk |= (unsigned long long)f2e4m3(f1.y*WSCALE) << 40;
    pk |= (unsigned long long)f2e4m3(f1.z*WSCALE) << 48;
    pk |= (unsigned long long)f2e4m3(f1.w*WSCALE) << 56;
    *(unsigned long long*)&lds[kl][n0] = pk;
  }
  __syncthreads();
  {
    const int ntl = tid >> 6, lane = tid & 63;
    const int kgrp = lane >> 4, n16 = lane & 15;
    unsigned long long pk = 0ull;
    #pragma unroll
    for (int p=0;p<8;p++)
      pk |= ((unsigned long long)lds[kgrp*8 + p][ntl*16 + n16]) << (8*p);
    Bp[((size_t)(nb*4 + ntl)*NKT + kt)*64 + lane] = pk;
  }
  // ---- fused init ----
  const int i = (kt*128 + nb)*256 + tid;
  if (i < 7*32*32){                     // x-embedding fragments, steps t=1..7
    const int s   = i >> 10;            // slot = t-1
    const int rem = i & 1023;
    const int b   = rem >> 5;
    const int kgi = rem & 31;           // which 8-byte k-group of EMB
    const int tk  = tok[b*TT + s];
    const float4 e0 = *(const float4*)(E + (size_t)tk*EMB + kgi*8);
    const float4 e1 = *(const float4*)(E + (size_t)tk*EMB + kgi*8 + 4);
    unsigned long long pk = 0ull;
    pk |= (unsigned long long)f2e4m3(e0.x*ASCALE);
    pk |= (unsigned long long)f2e4m3(e0.y*ASCALE) << 8;
    pk |= (unsigned long long)f2e4m3(e0.z*ASCALE) << 16;
    pk |= (unsigned long long)f2e4m3(e0.w*ASCALE) << 24;
    pk |= (unsigned long long)f2e4m3(e1.x*ASCALE) << 32;
    pk |= (unsigned long long)f2e4m3(e1.y*ASCALE) << 40;
    pk |= (unsigned long long)f2e4m3(e1.z*ASCALE) << 48;
    pk |= (unsigned long long)f2e4m3(e1.w*ASCALE) << 56;
    AfX[((size_t)((s*2 + (b>>4))*8 + (kgi>>2)))*64 + (kgi&3)*16 + (b&15)] = pk;
  }
  if (i < 8192) AfH1[i] = 0ull;         // t=1 reads parity-1 h-buffer: h0 = 0
  if (i < BATCH*LAT)
    out[(size_t)((i>>7)*TT + 0)*LAT + (i&(LAT-1))] = 0.f;  // t=0: z=0 exactly
  if (i < 4096) flg[i] = 0;
}

// All 7 LSTM steps + outputs in ONE persistent kernel, flat flag-synchronized.
// 256 blocks = (jt 0..127) x (mh 0..1); 4 waves = 4 gates; wave M=16 x N=16.
// B fragments pinned in VGPRs for the whole sequence. Cross-block data moves
// via relaxed agent-scope (sc1) atomics; per-block flag lines; ordering =
// vmcnt(0) + __syncthreads before the flag store. Per step: x-MFMAs hoisted
// before the flag wait; h-frags staged once per block through LDS.
// The out-column write is OUT of the step loop (it made blocks 0..31 per-step
// stragglers that gated the global wait) — all 7 output columns are written at
// the end, one (slot,b) pair per block over 224 blocks, concurrently. Values
// read are identical (flag-drain protected) -> output bit-identical.
__global__ __launch_bounds__(256, 1) void k_fused(
    const int* __restrict__ tok, const float* __restrict__ bias,
    float* __restrict__ out, float* __restrict__ Zp, float* __restrict__ Sp,
    float* __restrict__ Eac, const unsigned long long* __restrict__ AfX,
    unsigned long long* __restrict__ AfH, const unsigned long long* __restrict__ Bp,
    int* __restrict__ flg){
  const int tid = threadIdx.x;
  const int bid = blockIdx.x;
  const int jt = bid & 127, mh = bid >> 7;
  const int g = tid >> 6, lane = tid & 63;
  const int quad = lane >> 4, col = lane & 15;

  __shared__ float gsh[4][16][16];
  __shared__ long hlds[64][64];         // 32 KB: h-frag stage, conflict-free b64
  __shared__ unsigned char hsh[256];
  __shared__ float zsh[2];

  // ---- persistent B fragments: one n-tile per wave, full K, in registers ----
  const long* __restrict__ BpV = (const long*)Bp;
  const size_t bbase = (size_t)(g*NJT + jt)*NKT*64 + lane;
  long Breg[NKT];
  #pragma unroll
  for (int i=0;i<NKT;i++) Breg[i] = BpV[bbase + (size_t)i*64];
  #pragma unroll
  for (int i=0;i<NKT;i++) asm volatile("" : "+v"(Breg[i]));  // pin: no sinking

  // epilogue thread mapping: thread owns (b, j)
  const int b16 = tid >> 4, jj = tid & 15;
  const int b = mh*16 + b16;
  const int j = jt*16 + jj;
  const float bi  = bias[j];
  const float bff = bias[j + VOCAB];
  const float bgg = bias[j + 2*VOCAB];
  const float boo = bias[j + 3*VOCAB];
  const int hoff = ((jj>>3)&1)*128 + b16*8 + (jj&7);           // byte in hsh
  const size_t bofs = (size_t)(mh*64 + (jt>>1))*512 + (size_t)(jt&1)*256;
  float hreg = 0.f, creg = 0.f;

  for (int t=1; t<TT; t++){
    // A: x-part MFMA — independent of other blocks' step t-1
    const long* __restrict__ aX = (const long*)AfX + (size_t)((t-1)*2 + mh)*512 + lane;
    f32x4 acc = {0,0,0,0};
    #pragma unroll
    for (int kt=0; kt<8; kt++)
      acc = __builtin_amdgcn_mfma_f32_16x16x32_fp8_fp8(aX[(size_t)kt*64], Breg[kt], acc, 0,0,0);

    // B: wait for all 256 producers of step t-1 (64 pollers x 4 flags each)
    if (t >= 2){
      const int want = t-1;
      if (tid < 64){
        for (;;){
          int done = 1;
          #pragma unroll
          for (int q2=0;q2<4;q2++)
            done &= (AT_LD(&flg[(tid*4+q2)*16]) >= want) ? 1 : 0;
          if (done) break;
          __builtin_amdgcn_s_sleep(1);
        }
      }
      asm volatile("" ::: "memory");
    }
    __syncthreads();

    // C: stage h-frags to LDS — each wave loads only its 16 rows (sc1)
    {
      unsigned long long* aH = AfH + (size_t)(t&1)*8192 + (size_t)mh*4096;
      long hl[16];
      #pragma unroll
      for (int i=0;i<16;i++)
        hl[i] = (long)AT_LD(&aH[(size_t)(g*16+i)*64 + lane]);
      #pragma unroll
      for (int i=0;i<16;i++) hlds[g*16+i][lane] = hl[i];
    }
    __syncthreads();

    // D: h-part MFMA from LDS — identical kt order -> bit-identical acc
    #pragma unroll
    for (int kt=8; kt<NKT; kt++)
      acc = __builtin_amdgcn_mfma_f32_16x16x32_fp8_fp8(hlds[kt-8][lane], Breg[kt], acc, 0,0,0);
    #pragma unroll
    for (int r=0;r<4;r++) gsh[g][quad*4 + r][col] = acc[r];
    __syncthreads();

    // E: fused cell (same math/order as verified version)
    const float ip = gsh[0][b16][jj]*DQ + bi;
    const float fp = gsh[1][b16][jj]*DQ + bff;
    const float gg = gsh[2][b16][jj]*DQ + bgg;
    const float op = gsh[3][b16][jj]*DQ + boo;
    const float cn = sigmoidf_(fp)*creg + sigmoidf_(ip)*tanhf_(gg);
    const float hn = sigmoidf_(op)*tanhf_(cn);
    if (tok[b*TT + (t-1)] != 0){ hreg = hn; creg = cn; }
    hsh[hoff] = f2e4m3(ASCALE*hreg);
    const int sj = tok[b*TT + t];
    const float e = __expf(hreg);       // h in (-1,1): no max-pass
    if (j == sj) AT_ST(&Eac[(t-1)*32 + b], e);   // unique writer
    float z = e, s = (j < sj) ? e : 0.f;
    #pragma unroll
    for (int m=1; m<16; m<<=1){ z += __shfl_xor(z, m); s += __shfl_xor(s, m); }
    if (jj == 0){                       // contention-free partials (per jt)
      AT_ST(&Zp[((size_t)(t-1)*32 + b)*128 + jt], z);
      AT_ST(&Sp[((size_t)(t-1)*32 + b)*128 + jt], s);
    }
    __syncthreads();                    // hsh complete

    // F: publish h-frags, drain, post flag
    if (tid < 32){
      unsigned long long* dst =
        (unsigned long long*)((unsigned char*)AfH + (size_t)((t&1)^1)*65536 + bofs);
      AT_ST(&dst[tid], ((const unsigned long long*)hsh)[tid]);
    }
    asm volatile("s_waitcnt vmcnt(0)" ::: "memory");  // all sc1 stores at L3
    __syncthreads();
    if (tid == 0) AT_ST(&flg[bid*16], t);
  }

  // Tail: all 7 output columns, one (slot,b) pair per block (224 blocks),
  // concurrent — removes the per-step straggler that phase G used to create.
  if (bid < 7*BATCH){
    const int s = bid >> 5, b2 = bid & 31;
    if (tid < 64){
      for (;;){
        int done = 1;
        #pragma unroll
        for (int q2=0;q2<4;q2++)
          done &= (AT_LD(&flg[(tid*4+q2)*16]) >= TT-1) ? 1 : 0;
        if (done) break;
        __builtin_amdgcn_s_sleep(1);
      }
    }
    asm volatile("" ::: "memory");
    __syncthreads();
    if (tid < 64){
      float zl = AT_LD(&Zp[((size_t)s*32+b2)*128 + tid])
               + AT_LD(&Zp[((size_t)s*32+b2)*128 + tid + 64]);
      float sl = AT_LD(&Sp[((size_t)s*32+b2)*128 + tid])
               + AT_LD(&Sp[((size_t)s*32+b2)*128 + tid + 64]);
      #pragma unroll
      for (int m=1; m<64; m<<=1){ zl += __shfl_xor(zl, m); sl += __shfl_xor(sl, m); }
      if (tid == 0){ zsh[0] = zl; zsh[1] = sl; }
    }
    __syncthreads();
    if (tid < LAT){
      const float Ej = AT_LD(&Eac[s*32 + b2]);
      out[((size_t)b2*TT + (s+1))*LAT + tid] = (3.f*zsh[1] + 1.5f*Ej)/zsh[0];
    }
  }
}

extern "C" void kernel_launch(void* const* d_in, const int* in_sizes, int n_in,
                              void* d_out, int out_size, void* d_ws, size_t ws_size,
                              hipStream_t stream){
  const int*   tok  = (const int*)d_in[0];
  const float* E    = (const float*)d_in[1];
  const float* Wi   = (const float*)d_in[2];
  const float* Wh   = (const float*)d_in[3];
  const float* bias = (const float*)d_in[4];
  float* out = (float*)d_out;
  float* ws  = (float*)d_ws;
  float* Eac = ws + EAC_OFF;
  int*   flg = (int*)(ws + FLG_OFF);
  float* Zp  = ws + ZP_OFF;
  float* Sp  = ws + SP_OFF;
  unsigned long long* AfX = (unsigned long long*)(ws + AFX_OFF);
  unsigned long long* AfH = (unsigned long long*)(ws + AFH_OFF);
  unsigned long long* Bp  = (unsigned long long*)(ws + BP_OFF);

  k_pack<<<dim3(128, NKT), 256, 0, stream>>>(tok, E, Wi, Wh, Bp, AfX, AfH + 8192,
                                             flg, out);
  k_fused<<<256, 256, 0, stream>>>(tok, bias, out, Zp, Sp, Eac, AfX, AfH, Bp, flg);
}